// Round 1
// baseline (1373.853 us; speedup 1.0000x reference)
//
#include <hip/hip_runtime.h>
#include <math.h>

#define T_SEQ 1024
#define TA_SEQ 1024
#define BATCH 8
#define CH 1024
#define NH 16
#define HD 64
#define MH 4096

typedef unsigned short u16;
typedef unsigned short u16x4 __attribute__((ext_vector_type(4)));
typedef unsigned short u16x8 __attribute__((ext_vector_type(8)));
typedef __bf16 bf16x8 __attribute__((ext_vector_type(8)));
typedef float f32x4 __attribute__((ext_vector_type(4)));

__device__ __forceinline__ u16 f2bf(float f) {
  unsigned int u = __builtin_bit_cast(unsigned int, f);
  u += 0x7FFFu + ((u >> 16) & 1u);   // RNE
  return (u16)(u >> 16);
}
__device__ __forceinline__ bf16x8 ldbf8(const u16* p) {
  return __builtin_bit_cast(bf16x8, *reinterpret_cast<const u16x8*>(p));
}

// ------------- weight transpose-convert: fp32 in[K][N] -> bf16 out[N][K] -------------
__global__ void k_transpose_w(const float* __restrict__ in, u16* __restrict__ out,
                              int K, int N) {
  __shared__ float tile[32][33];
  int n0 = blockIdx.x * 32, k0 = blockIdx.y * 32;
  int tx = threadIdx.x, ty = threadIdx.y;   // block (32,8)
#pragma unroll
  for (int i = 0; i < 4; i++)
    tile[ty + i * 8][tx] = in[(size_t)(k0 + ty + i * 8) * N + n0 + tx];
  __syncthreads();
#pragma unroll
  for (int i = 0; i < 4; i++)
    out[(size_t)(n0 + ty + i * 8) * K + k0 + tx] = f2bf(tile[tx][ty + i * 8]);
}

// ------------- adaLN modulation: mod[b][6C] = silu(c[b]) @ w_ada + b_ada -------------
__global__ void k_ada(const float* __restrict__ c, const float* __restrict__ w_ada,
                      const float* __restrict__ b_ada, float* __restrict__ mod) {
  __shared__ float sc[CH];
  int b = blockIdx.y;
  int tid = threadIdx.x;
  for (int i = tid; i < CH; i += 256) {
    float cv = c[b * CH + i];
    sc[i] = cv / (1.0f + expf(-cv));   // silu
  }
  __syncthreads();
  int n = blockIdx.x * 256 + tid;
  float acc = 0.0f;
  for (int k = 0; k < CH; k++) acc += sc[k] * w_ada[(size_t)k * (6 * CH) + n];
  mod[(size_t)b * (6 * CH) + n] = acc + b_ada[n];
}

// ------------- [T][B][C] fp32 -> batch-major [B*T][C] (fp32 / bf16) -------------
__global__ void k_tbc_to_btc_f32(const float* __restrict__ in, float* __restrict__ out) {
  size_t i = (size_t)blockIdx.x * 256 + threadIdx.x;
  int c = (int)(i & (CH - 1));
  size_t tb = i >> 10;
  int b = (int)(tb & (BATCH - 1));
  size_t t = tb >> 3;
  out[((size_t)b * T_SEQ + t) * CH + c] = in[i];
}
__global__ void k_tbc_to_btc_bf16(const float* __restrict__ in, u16* __restrict__ out) {
  size_t i = (size_t)blockIdx.x * 256 + threadIdx.x;
  int c = (int)(i & (CH - 1));
  size_t tb = i >> 10;
  int b = (int)(tb & (BATCH - 1));
  size_t t = tb >> 3;
  out[((size_t)b * TA_SEQ + t) * CH + c] = f2bf(in[i]);
}

// ------------- LayerNorm (eps 1e-6, no affine) + modulate -> bf16 rows -------------
__global__ void k_ln_mod(const float* __restrict__ xb, const float* __restrict__ mod,
                         u16* __restrict__ out, int shift_sel, int scale_sel) {
  int row = blockIdx.x;          // 0..B*T-1  (batch-major, b = row>>10)
  int b = row >> 10;
  int tid = threadIdx.x;         // 256
  const float* xr = xb + (size_t)row * CH;
  float4 v = reinterpret_cast<const float4*>(xr)[tid];
  float s = v.x + v.y + v.z + v.w;
  float s2 = v.x * v.x + v.y * v.y + v.z * v.z + v.w * v.w;
#pragma unroll
  for (int off = 32; off > 0; off >>= 1) {
    s += __shfl_down(s, off);
    s2 += __shfl_down(s2, off);
  }
  __shared__ float red[8];
  __shared__ float stats[2];
  int wid = tid >> 6;
  if ((tid & 63) == 0) { red[wid] = s; red[4 + wid] = s2; }
  __syncthreads();
  if (tid == 0) {
    float a = red[0] + red[1] + red[2] + red[3];
    float a2 = red[4] + red[5] + red[6] + red[7];
    float mu = a * (1.0f / CH);
    float var = a2 * (1.0f / CH) - mu * mu;
    stats[0] = mu;
    stats[1] = rsqrtf(var + 1e-6f);
  }
  __syncthreads();
  float mu = stats[0], rs = stats[1];
  int c0 = tid * 4;
  const float* sh = mod + (size_t)b * (6 * CH) + (size_t)shift_sel * CH + c0;
  const float* scl = mod + (size_t)b * (6 * CH) + (size_t)scale_sel * CH + c0;
  float xs[4] = {v.x, v.y, v.z, v.w};
  u16x4 o;
#pragma unroll
  for (int j = 0; j < 4; j++)
    o[j] = f2bf((xs[j] - mu) * rs * (1.0f + scl[j]) + sh[j]);
  *reinterpret_cast<u16x4*>(out + (size_t)row * CH + c0) = o;
}

// ------------- MFMA GEMM: C[M,N] = A[M,K](bf16) @ Bt[N,K](bf16)^T, fused epilogues ----
// EPI 0: out_bf = bf16(acc + bias)
// EPI 1: xb[row*N+col] += mod[gate][col] * (acc + bias)   (residual gate add, fp32)
// EPI 2: out_bf = bf16(gelu_tanh(acc + bias))
template <int EPI>
__global__ __launch_bounds__(256) void k_gemm(
    const u16* __restrict__ A, const u16* __restrict__ Bt,
    const float* __restrict__ bias, u16* __restrict__ out_bf,
    float* __restrict__ xb, const float* __restrict__ mod, int gate_sel,
    int M, int N, int K) {
  __shared__ u16 As[128][40];   // stride 40 (80B): 16B-aligned frag reads, ~2-way banks
  __shared__ u16 Bs[128][40];
  int m0 = blockIdx.x * 128;
  int n0 = blockIdx.y * 128;
  int tid = threadIdx.x;
  int wid = tid >> 6, lane = tid & 63;
  int wm = (wid >> 1) * 64, wn = (wid & 1) * 64;
  int lrow = lane & 15, quad = lane >> 4;

  f32x4 zero4 = {0.f, 0.f, 0.f, 0.f};
  f32x4 acc[4][4];
#pragma unroll
  for (int mi = 0; mi < 4; mi++)
#pragma unroll
    for (int ni = 0; ni < 4; ni++) acc[mi][ni] = zero4;

  int ar = tid >> 1;             // 0..127 (tile row)
  int ac = (tid & 1) * 16;       // 0 / 16
  const int kiters = K >> 5;
  for (int kt = 0; kt < kiters; kt++) {
    int k0 = kt << 5;
    u16x8 a0 = *reinterpret_cast<const u16x8*>(A + (size_t)(m0 + ar) * K + k0 + ac);
    u16x8 a1 = *reinterpret_cast<const u16x8*>(A + (size_t)(m0 + ar) * K + k0 + ac + 8);
    u16x8 b0 = *reinterpret_cast<const u16x8*>(Bt + (size_t)(n0 + ar) * K + k0 + ac);
    u16x8 b1 = *reinterpret_cast<const u16x8*>(Bt + (size_t)(n0 + ar) * K + k0 + ac + 8);
    __syncthreads();
    *reinterpret_cast<u16x8*>(&As[ar][ac]) = a0;
    *reinterpret_cast<u16x8*>(&As[ar][ac + 8]) = a1;
    *reinterpret_cast<u16x8*>(&Bs[ar][ac]) = b0;
    *reinterpret_cast<u16x8*>(&Bs[ar][ac + 8]) = b1;
    __syncthreads();
    bf16x8 af[4], bfr[4];
#pragma unroll
    for (int mi = 0; mi < 4; mi++)
      af[mi] = ldbf8(&As[wm + mi * 16 + lrow][quad * 8]);
#pragma unroll
    for (int ni = 0; ni < 4; ni++)
      bfr[ni] = ldbf8(&Bs[wn + ni * 16 + lrow][quad * 8]);
#pragma unroll
    for (int mi = 0; mi < 4; mi++)
#pragma unroll
      for (int ni = 0; ni < 4; ni++)
        acc[mi][ni] = __builtin_amdgcn_mfma_f32_16x16x32_bf16(af[mi], bfr[ni],
                                                              acc[mi][ni], 0, 0, 0);
  }
  // epilogue: C row = quad*4+r, col = lrow (m89/m91-verified layout)
#pragma unroll
  for (int mi = 0; mi < 4; mi++)
#pragma unroll
    for (int ni = 0; ni < 4; ni++) {
      int col = n0 + wn + ni * 16 + lrow;
      float bval = bias[col];
#pragma unroll
      for (int r = 0; r < 4; r++) {
        int row = m0 + wm + mi * 16 + quad * 4 + r;
        float v = acc[mi][ni][r] + bval;
        if (EPI == 0) {
          out_bf[(size_t)row * N + col] = f2bf(v);
        } else if (EPI == 1) {
          int b = row >> 10;   // T=1024 rows per batch
          float g = mod[(size_t)b * (6 * CH) + (size_t)gate_sel * CH + col];
          xb[(size_t)row * N + col] += g * v;
        } else {
          float t = 0.79788456080286536f * (v + 0.044715f * v * v * v);
          float gel = 0.5f * v * (1.0f + tanhf(t));
          out_bf[(size_t)row * N + col] = f2bf(gel);
        }
      }
    }
}

// ------------- flash attention: Q[B*Tq,C], K/V[B*Tk,C] bf16, mask[B,Tk] int ---------
__global__ __launch_bounds__(256) void k_attn(
    const u16* __restrict__ Q, const u16* __restrict__ Kb, const u16* __restrict__ Vb,
    const int* __restrict__ mask, u16* __restrict__ Y, int Tq, int Tk) {
  int qt = blockIdx.x, h = blockIdx.y, b = blockIdx.z;
  int tid = threadIdx.x, wid = tid >> 6, lane = tid & 63;
  int lrow = lane & 15, quad = lane >> 4;

  // per-lane Q A-fragments (A[m=lane&15][k=quad*8+j], two K=32 slices over D=64)
  int qrow = qt * 64 + wid * 16 + lrow;
  size_t qoff = ((size_t)(b * Tq + qrow)) * CH + h * HD;
  bf16x8 aq0 = ldbf8(Q + qoff + quad * 8);
  bf16x8 aq1 = ldbf8(Q + qoff + 32 + quad * 8);

  __shared__ u16 VT[64][40];       // V^T tile: [d][key], shared by the 4 waves
  __shared__ u16 P[4][16][40];     // per-wave P scratch: [q][key(32)]

  f32x4 zero4 = {0.f, 0.f, 0.f, 0.f};
  f32x4 o[4];
  float m_i[4], l_i[4];
#pragma unroll
  for (int r = 0; r < 4; r++) { o[r] = zero4; m_i[r] = -INFINITY; l_i[r] = 0.f; }

  const int* mrow = mask + (size_t)b * Tk;
  for (int kt = 0; kt < Tk / 32; kt++) {
    int kb = kt * 32;
    __syncthreads();   // protect VT from previous iteration's readers
    {
      int key_l = tid >> 3;          // 0..31
      int d0 = (tid & 7) * 8;        // 0..56
      u16x8 vv = *reinterpret_cast<const u16x8*>(
          Vb + ((size_t)(b * Tk + kb + key_l)) * CH + h * HD + d0);
#pragma unroll
      for (int j = 0; j < 8; j++) VT[d0 + j][key_l] = vv[j];
    }
    __syncthreads();

    // S = Q K^T * 0.125, masked
    f32x4 s[2];
#pragma unroll
    for (int sub = 0; sub < 2; sub++) {
      int key = kb + sub * 16 + lrow;
      size_t koff = ((size_t)(b * Tk + key)) * CH + h * HD;
      bf16x8 bk0 = ldbf8(Kb + koff + quad * 8);
      bf16x8 bk1 = ldbf8(Kb + koff + 32 + quad * 8);
      f32x4 z = zero4;
      z = __builtin_amdgcn_mfma_f32_16x16x32_bf16(aq0, bk0, z, 0, 0, 0);
      z = __builtin_amdgcn_mfma_f32_16x16x32_bf16(aq1, bk1, z, 0, 0, 0);
      bool masked = (mrow[key] != 0);
#pragma unroll
      for (int r = 0; r < 4; r++)
        s[sub][r] = masked ? -INFINITY : z[r] * 0.125f;
    }
    // online softmax (rows = quad*4+r; 16 col-lanes reduced via shfl_xor)
    float rmax[4], rsum[4], alpha[4];
#pragma unroll
    for (int r = 0; r < 4; r++) rmax[r] = fmaxf(s[0][r], s[1][r]);
#pragma unroll
    for (int off = 1; off < 16; off <<= 1)
#pragma unroll
      for (int r = 0; r < 4; r++) rmax[r] = fmaxf(rmax[r], __shfl_xor(rmax[r], off));
#pragma unroll
    for (int r = 0; r < 4; r++) {
      float mnew = fmaxf(m_i[r], rmax[r]);
      alpha[r] = (m_i[r] == -INFINITY) ? 0.f : expf(m_i[r] - mnew);
      m_i[r] = mnew;
#pragma unroll
      for (int sub = 0; sub < 2; sub++)
        s[sub][r] = (s[sub][r] == -INFINITY) ? 0.f : expf(s[sub][r] - mnew);
      rsum[r] = s[0][r] + s[1][r];
    }
#pragma unroll
    for (int off = 1; off < 16; off <<= 1)
#pragma unroll
      for (int r = 0; r < 4; r++) rsum[r] += __shfl_xor(rsum[r], off);
#pragma unroll
    for (int r = 0; r < 4; r++) l_i[r] = l_i[r] * alpha[r] + rsum[r];
#pragma unroll
    for (int dc = 0; dc < 4; dc++)
#pragma unroll
      for (int r = 0; r < 4; r++) o[dc][r] *= alpha[r];

    // P: C-layout -> A-layout via wave-private LDS (no barrier needed)
#pragma unroll
    for (int sub = 0; sub < 2; sub++)
#pragma unroll
      for (int r = 0; r < 4; r++)
        P[wid][quad * 4 + r][sub * 16 + lrow] = f2bf(s[sub][r]);
    bf16x8 pf = ldbf8(&P[wid][lrow][quad * 8]);
#pragma unroll
    for (int dc = 0; dc < 4; dc++) {
      bf16x8 vf = ldbf8(&VT[dc * 16 + lrow][quad * 8]);
      o[dc] = __builtin_amdgcn_mfma_f32_16x16x32_bf16(pf, vf, o[dc], 0, 0, 0);
    }
  }
  // write Y (rows quad*4+r, col d = dc*16+lrow)
#pragma unroll
  for (int dc = 0; dc < 4; dc++)
#pragma unroll
    for (int r = 0; r < 4; r++) {
      int qr = qt * 64 + wid * 16 + quad * 4 + r;
      float val = o[dc][r] / l_i[r];
      Y[((size_t)(b * Tq + qr)) * CH + h * HD + dc * 16 + lrow] = f2bf(val);
    }
}

// ------------- final: batch-major xb -> out [T][B][C] fp32 -------------
__global__ void k_out(const float* __restrict__ xb, float* __restrict__ out) {
  size_t i = (size_t)blockIdx.x * 256 + threadIdx.x;
  int c = (int)(i & (CH - 1));
  size_t tb = i >> 10;
  int b = (int)(tb & (BATCH - 1));
  size_t t = tb >> 3;
  out[i] = xb[((size_t)b * T_SEQ + t) * CH + c];
}

extern "C" void kernel_launch(void* const* d_in, const int* in_sizes, int n_in,
                              void* d_out, int out_size, void* d_ws, size_t ws_size,
                              hipStream_t stream) {
  const float* x     = (const float*)d_in[0];
  const float* c     = (const float*)d_in[1];
  const int*   pmask = (const int*)d_in[2];
  const float* audio = (const float*)d_in[3];
  const int*   amask = (const int*)d_in[4];
  const float* w_ada = (const float*)d_in[5];
  const float* b_ada = (const float*)d_in[6];
  const float* wq = (const float*)d_in[7];  const float* bq = (const float*)d_in[8];
  const float* wk = (const float*)d_in[9];  const float* bk = (const float*)d_in[10];
  const float* wv = (const float*)d_in[11]; const float* bv = (const float*)d_in[12];
  const float* wo = (const float*)d_in[13]; const float* bo = (const float*)d_in[14];
  const float* cwq = (const float*)d_in[15]; const float* cbq = (const float*)d_in[16];
  const float* cwk = (const float*)d_in[17]; const float* cbk = (const float*)d_in[18];
  const float* cwv = (const float*)d_in[19]; const float* cbv = (const float*)d_in[20];
  const float* cwo = (const float*)d_in[21]; const float* cbo = (const float*)d_in[22];
  const float* w1 = (const float*)d_in[23]; const float* b1 = (const float*)d_in[24];
  const float* w2 = (const float*)d_in[25]; const float* b2 = (const float*)d_in[26];

  char* wsb = (char*)d_ws;
  size_t off = 0;
  auto alloc = [&](size_t bytes) {
    char* p = wsb + off;
    off += (bytes + 255) & ~(size_t)255;
    return p;
  };
  const size_t SQ = (size_t)CH * CH * 2;       // 2MB bf16 square weight
  u16* wqT  = (u16*)alloc(SQ);
  u16* wkT  = (u16*)alloc(SQ);
  u16* wvT  = (u16*)alloc(SQ);
  u16* woT  = (u16*)alloc(SQ);
  u16* cwqT = (u16*)alloc(SQ);
  u16* cwkT = (u16*)alloc(SQ);
  u16* cwvT = (u16*)alloc(SQ);
  u16* cwoT = (u16*)alloc(SQ);
  u16* w1T  = (u16*)alloc((size_t)CH * MH * 2);
  u16* w2T  = (u16*)alloc((size_t)CH * MH * 2);
  float* mod = (float*)alloc((size_t)BATCH * 6 * CH * 4);
  float* xb  = (float*)alloc((size_t)BATCH * T_SEQ * CH * 4);
  u16* xm    = (u16*)alloc((size_t)BATCH * T_SEQ * CH * 2);
  u16* qbuf  = (u16*)alloc((size_t)BATCH * T_SEQ * CH * 2);   // these four are
  u16* kbuf  = (u16*)alloc((size_t)BATCH * T_SEQ * CH * 2);   // contiguous: hbuf
  u16* vbuf  = (u16*)alloc((size_t)BATCH * T_SEQ * CH * 2);   // (8192x4096 bf16)
  u16* ybuf  = (u16*)alloc((size_t)BATCH * T_SEQ * CH * 2);   // aliases them
  u16* hbuf  = qbuf;
  u16* abuf  = (u16*)alloc((size_t)BATCH * TA_SEQ * CH * 2);
  (void)ws_size; (void)in_sizes; (void)n_in; (void)out_size;

  const int NE = T_SEQ * BATCH * CH;   // 8.39M elements
  dim3 tb32(32, 8);

  // weights -> bf16 transposed
  k_transpose_w<<<dim3(CH / 32, CH / 32), tb32, 0, stream>>>(wq, wqT, CH, CH);
  k_transpose_w<<<dim3(CH / 32, CH / 32), tb32, 0, stream>>>(wk, wkT, CH, CH);
  k_transpose_w<<<dim3(CH / 32, CH / 32), tb32, 0, stream>>>(wv, wvT, CH, CH);
  k_transpose_w<<<dim3(CH / 32, CH / 32), tb32, 0, stream>>>(wo, woT, CH, CH);
  k_transpose_w<<<dim3(CH / 32, CH / 32), tb32, 0, stream>>>(cwq, cwqT, CH, CH);
  k_transpose_w<<<dim3(CH / 32, CH / 32), tb32, 0, stream>>>(cwk, cwkT, CH, CH);
  k_transpose_w<<<dim3(CH / 32, CH / 32), tb32, 0, stream>>>(cwv, cwvT, CH, CH);
  k_transpose_w<<<dim3(CH / 32, CH / 32), tb32, 0, stream>>>(cwo, cwoT, CH, CH);
  k_transpose_w<<<dim3(MH / 32, CH / 32), tb32, 0, stream>>>(w1, w1T, CH, MH);
  k_transpose_w<<<dim3(CH / 32, MH / 32), tb32, 0, stream>>>(w2, w2T, MH, CH);

  k_ada<<<dim3(6 * CH / 256, BATCH), 256, 0, stream>>>(c, w_ada, b_ada, mod);
  k_tbc_to_btc_f32<<<NE / 256, 256, 0, stream>>>(x, xb);
  k_tbc_to_btc_bf16<<<NE / 256, 256, 0, stream>>>(audio, abuf);

  // ---- self-attention ----
  k_ln_mod<<<BATCH * T_SEQ, 256, 0, stream>>>(xb, mod, xm, 0, 1);
  k_gemm<0><<<dim3(64, 8), 256, 0, stream>>>(xm, wqT, bq, qbuf, nullptr, nullptr, 0, 8192, CH, CH);
  k_gemm<0><<<dim3(64, 8), 256, 0, stream>>>(xm, wkT, bk, kbuf, nullptr, nullptr, 0, 8192, CH, CH);
  k_gemm<0><<<dim3(64, 8), 256, 0, stream>>>(xm, wvT, bv, vbuf, nullptr, nullptr, 0, 8192, CH, CH);
  k_attn<<<dim3(T_SEQ / 64, NH, BATCH), 256, 0, stream>>>(qbuf, kbuf, vbuf, pmask, ybuf, T_SEQ, T_SEQ);
  k_gemm<1><<<dim3(64, 8), 256, 0, stream>>>(ybuf, woT, bo, nullptr, xb, mod, 2, 8192, CH, CH);

  // ---- cross-attention (reuses msa shift/scale/gate) ----
  k_ln_mod<<<BATCH * T_SEQ, 256, 0, stream>>>(xb, mod, xm, 0, 1);
  k_gemm<0><<<dim3(64, 8), 256, 0, stream>>>(xm, cwqT, cbq, qbuf, nullptr, nullptr, 0, 8192, CH, CH);
  k_gemm<0><<<dim3(64, 8), 256, 0, stream>>>(abuf, cwkT, cbk, kbuf, nullptr, nullptr, 0, 8192, CH, CH);
  k_gemm<0><<<dim3(64, 8), 256, 0, stream>>>(abuf, cwvT, cbv, vbuf, nullptr, nullptr, 0, 8192, CH, CH);
  k_attn<<<dim3(T_SEQ / 64, NH, BATCH), 256, 0, stream>>>(qbuf, kbuf, vbuf, amask, ybuf, T_SEQ, TA_SEQ);
  k_gemm<1><<<dim3(64, 8), 256, 0, stream>>>(ybuf, cwoT, cbo, nullptr, xb, mod, 2, 8192, CH, CH);

  // ---- MLP ----
  k_ln_mod<<<BATCH * T_SEQ, 256, 0, stream>>>(xb, mod, xm, 3, 4);
  k_gemm<2><<<dim3(64, 32), 256, 0, stream>>>(xm, w1T, b1, hbuf, nullptr, nullptr, 0, 8192, MH, CH);
  k_gemm<1><<<dim3(64, 8), 256, 0, stream>>>(hbuf, w2T, b2, nullptr, xb, mod, 5, 8192, CH, MH);

  k_out<<<NE / 256, 256, 0, stream>>>(xb, (float*)d_out);
}

// Round 2
// 1354.388 us; speedup vs baseline: 1.0144x; 1.0144x over previous
//
#include <hip/hip_runtime.h>
#include <math.h>

#define T_SEQ 1024
#define TA_SEQ 1024
#define BATCH 8
#define CH 1024
#define NH 16
#define HD 64
#define MH 4096

typedef unsigned short u16;
typedef unsigned short u16x4 __attribute__((ext_vector_type(4)));
typedef unsigned short u16x8 __attribute__((ext_vector_type(8)));
typedef __bf16 bf16x8 __attribute__((ext_vector_type(8)));
typedef float f32x4 __attribute__((ext_vector_type(4)));

__device__ __forceinline__ u16 f2bf(float f) {
  unsigned int u = __builtin_bit_cast(unsigned int, f);
  u += 0x7FFFu + ((u >> 16) & 1u);   // RNE
  return (u16)(u >> 16);
}
__device__ __forceinline__ u16 f2bf_trunc(float f) {   // cheap cvt for P (values in [0,1])
  return (u16)(__builtin_bit_cast(unsigned int, f) >> 16);
}
__device__ __forceinline__ bf16x8 ldbf8(const u16* p) {
  return __builtin_bit_cast(bf16x8, *reinterpret_cast<const u16x8*>(p));
}
// async global->LDS, 16B per lane (dest must be wave-uniform base + lane*16)
__device__ __forceinline__ void gload_lds16(const u16* g, u16* l) {
  __builtin_amdgcn_global_load_lds(
      (const __attribute__((address_space(1))) unsigned int*)g,
      (__attribute__((address_space(3))) unsigned int*)l, 16, 0, 0);
}

// ------------- weight transpose-convert: fp32 in[K][N] -> bf16 out[N][K] -------------
__global__ void k_transpose_w(const float* __restrict__ in, u16* __restrict__ out,
                              int K, int N) {
  __shared__ float tile[32][33];
  int n0 = blockIdx.x * 32, k0 = blockIdx.y * 32;
  int tx = threadIdx.x, ty = threadIdx.y;   // block (32,8)
#pragma unroll
  for (int i = 0; i < 4; i++)
    tile[ty + i * 8][tx] = in[(size_t)(k0 + ty + i * 8) * N + n0 + tx];
  __syncthreads();
#pragma unroll
  for (int i = 0; i < 4; i++)
    out[(size_t)(n0 + ty + i * 8) * K + k0 + tx] = f2bf(tile[tx][ty + i * 8]);
}

// ------------- adaLN modulation: mod[b][6C] = silu(c[b]) @ w_ada + b_ada -------------
__global__ void k_ada(const float* __restrict__ c, const float* __restrict__ w_ada,
                      const float* __restrict__ b_ada, float* __restrict__ mod) {
  __shared__ float sc[CH];
  int b = blockIdx.y;
  int tid = threadIdx.x;
  for (int i = tid; i < CH; i += 256) {
    float cv = c[b * CH + i];
    sc[i] = cv / (1.0f + expf(-cv));   // silu
  }
  __syncthreads();
  int n = blockIdx.x * 256 + tid;
  float acc = 0.0f;
  for (int k = 0; k < CH; k++) acc += sc[k] * w_ada[(size_t)k * (6 * CH) + n];
  mod[(size_t)b * (6 * CH) + n] = acc + b_ada[n];
}

// ------------- [T][B][C] fp32 -> batch-major [B*T][C] (fp32 / bf16) -------------
__global__ void k_tbc_to_btc_f32(const float* __restrict__ in, float* __restrict__ out) {
  size_t i = (size_t)blockIdx.x * 256 + threadIdx.x;
  int c = (int)(i & (CH - 1));
  size_t tb = i >> 10;
  int b = (int)(tb & (BATCH - 1));
  size_t t = tb >> 3;
  out[((size_t)b * T_SEQ + t) * CH + c] = in[i];
}
__global__ void k_tbc_to_btc_bf16(const float* __restrict__ in, u16* __restrict__ out) {
  size_t i = (size_t)blockIdx.x * 256 + threadIdx.x;
  int c = (int)(i & (CH - 1));
  size_t tb = i >> 10;
  int b = (int)(tb & (BATCH - 1));
  size_t t = tb >> 3;
  out[((size_t)b * TA_SEQ + t) * CH + c] = f2bf(in[i]);
}

// ------------- LayerNorm (eps 1e-6, no affine) + modulate -> bf16 rows -------------
__global__ void k_ln_mod(const float* __restrict__ xb, const float* __restrict__ mod,
                         u16* __restrict__ out, int shift_sel, int scale_sel) {
  int row = blockIdx.x;          // 0..B*T-1  (batch-major, b = row>>10)
  int b = row >> 10;
  int tid = threadIdx.x;         // 256
  const float* xr = xb + (size_t)row * CH;
  float4 v = reinterpret_cast<const float4*>(xr)[tid];
  float s = v.x + v.y + v.z + v.w;
  float s2 = v.x * v.x + v.y * v.y + v.z * v.z + v.w * v.w;
#pragma unroll
  for (int off = 32; off > 0; off >>= 1) {
    s += __shfl_down(s, off);
    s2 += __shfl_down(s2, off);
  }
  __shared__ float red[8];
  __shared__ float stats[2];
  int wid = tid >> 6;
  if ((tid & 63) == 0) { red[wid] = s; red[4 + wid] = s2; }
  __syncthreads();
  if (tid == 0) {
    float a = red[0] + red[1] + red[2] + red[3];
    float a2 = red[4] + red[5] + red[6] + red[7];
    float mu = a * (1.0f / CH);
    float var = a2 * (1.0f / CH) - mu * mu;
    stats[0] = mu;
    stats[1] = rsqrtf(var + 1e-6f);
  }
  __syncthreads();
  float mu = stats[0], rs = stats[1];
  int c0 = tid * 4;
  const float* sh = mod + (size_t)b * (6 * CH) + (size_t)shift_sel * CH + c0;
  const float* scl = mod + (size_t)b * (6 * CH) + (size_t)scale_sel * CH + c0;
  float xs[4] = {v.x, v.y, v.z, v.w};
  u16x4 o;
#pragma unroll
  for (int j = 0; j < 4; j++)
    o[j] = f2bf((xs[j] - mu) * rs * (1.0f + scl[j]) + sh[j]);
  *reinterpret_cast<u16x4*>(out + (size_t)row * CH + c0) = o;
}

// ------------- MFMA GEMM: C[M,N] = A[M,K](bf16) @ Bt[N,K](bf16)^T, fused epilogues ----
// EPI 0: out_bf = bf16(acc + bias)
// EPI 1: xb[row*N+col] += mod[gate][col] * (acc + bias)   (residual gate add, fp32)
// EPI 2: out_bf = bf16(gelu_tanh(acc + bias))
// EPI 3: out_bf = bf16((acc + bias) * 0.125*log2e)        (pre-scaled Q for attention)
template <int EPI>
__global__ __launch_bounds__(256) void k_gemm(
    const u16* __restrict__ A, const u16* __restrict__ Bt,
    const float* __restrict__ bias, u16* __restrict__ out_bf,
    float* __restrict__ xb, const float* __restrict__ mod, int gate_sel,
    int M, int N, int K) {
  // unpadded, lane-contiguous layout required by global_load_lds (m104/m108)
  __shared__ u16 As[128 * 32];
  __shared__ u16 Bs[128 * 32];
  int m0 = blockIdx.x * 128;
  int n0 = blockIdx.y * 128;
  int tid = threadIdx.x;
  int wid = tid >> 6, lane = tid & 63;
  int wm = (wid >> 1) * 64, wn = (wid & 1) * 64;
  int lrow = lane & 15, quad = lane >> 4;

  f32x4 zero4 = {0.f, 0.f, 0.f, 0.f};
  f32x4 acc[4][4];
#pragma unroll
  for (int mi = 0; mi < 4; mi++)
#pragma unroll
    for (int ni = 0; ni < 4; ni++) acc[mi][ni] = zero4;

  // chunk mapping: chunk i (0..511) -> LDS 16B at i*16; global row i>>2, col8 (i&3)*8
  int c0 = tid, c1 = 256 + tid;
  const u16* ga0 = A + (size_t)(m0 + (c0 >> 2)) * K + (c0 & 3) * 8;
  const u16* ga1 = A + (size_t)(m0 + (c1 >> 2)) * K + (c1 & 3) * 8;
  const u16* gb0 = Bt + (size_t)(n0 + (c0 >> 2)) * K + (c0 & 3) * 8;
  const u16* gb1 = Bt + (size_t)(n0 + (c1 >> 2)) * K + (c1 & 3) * 8;
  u16* la0 = As + c0 * 8;
  u16* la1 = As + c1 * 8;
  u16* lb0 = Bs + c0 * 8;
  u16* lb1 = Bs + c1 * 8;

  const int kiters = K >> 5;
  for (int kt = 0; kt < kiters; kt++) {
    int k0 = kt << 5;
    __syncthreads();                 // prev iteration's frag reads done
    gload_lds16(ga0 + k0, la0);
    gload_lds16(ga1 + k0, la1);
    gload_lds16(gb0 + k0, lb0);
    gload_lds16(gb1 + k0, lb1);
    __syncthreads();                 // drains vmcnt -> staged data visible
    bf16x8 af[4], bfr[4];
#pragma unroll
    for (int mi = 0; mi < 4; mi++)
      af[mi] = ldbf8(&As[(wm + mi * 16 + lrow) * 32 + quad * 8]);
#pragma unroll
    for (int ni = 0; ni < 4; ni++)
      bfr[ni] = ldbf8(&Bs[(wn + ni * 16 + lrow) * 32 + quad * 8]);
#pragma unroll
    for (int mi = 0; mi < 4; mi++)
#pragma unroll
      for (int ni = 0; ni < 4; ni++)
        acc[mi][ni] = __builtin_amdgcn_mfma_f32_16x16x32_bf16(af[mi], bfr[ni],
                                                              acc[mi][ni], 0, 0, 0);
  }
  // epilogue: C row = quad*4+r, col = lrow (m89/m91-verified layout)
#pragma unroll
  for (int mi = 0; mi < 4; mi++)
#pragma unroll
    for (int ni = 0; ni < 4; ni++) {
      int col = n0 + wn + ni * 16 + lrow;
      float bval = bias[col];
#pragma unroll
      for (int r = 0; r < 4; r++) {
        int row = m0 + wm + mi * 16 + quad * 4 + r;
        float v = acc[mi][ni][r] + bval;
        if (EPI == 0) {
          out_bf[(size_t)row * N + col] = f2bf(v);
        } else if (EPI == 1) {
          int b = row >> 10;   // T=1024 rows per batch
          float g = mod[(size_t)b * (6 * CH) + (size_t)gate_sel * CH + col];
          xb[(size_t)row * N + col] += g * v;
        } else if (EPI == 2) {
          float t = 0.79788456080286536f * (v + 0.044715f * v * v * v);
          float gel = 0.5f * v * (1.0f + tanhf(t));
          out_bf[(size_t)row * N + col] = f2bf(gel);
        } else {
          out_bf[(size_t)row * N + col] = f2bf(v * 0.18033688011112042f);
        }
      }
    }
}

// ------------- flash attention (exp2 domain; Q pre-scaled by 0.125*log2e) ---------
// 64-key tiles; l accumulated via ones-row V channel (5th MFMA output block).
__global__ __launch_bounds__(256) void k_attn(
    const u16* __restrict__ Q, const u16* __restrict__ Kb, const u16* __restrict__ Vb,
    const int* __restrict__ mask, u16* __restrict__ Y, int Tq, int Tk) {
  int qt = blockIdx.x, h = blockIdx.y, b = blockIdx.z;
  int tid = threadIdx.x, wid = tid >> 6, lane = tid & 63;
  int lrow = lane & 15, quad = lane >> 4;

  // per-lane Q A-fragments (A[m=lane&15][k=quad*8+j], two K=32 slices over D=64)
  int qrow = qt * 64 + wid * 16 + lrow;
  size_t qoff = ((size_t)(b * Tq + qrow)) * CH + h * HD;
  bf16x8 aq0 = ldbf8(Q + qoff + quad * 8);
  bf16x8 aq1 = ldbf8(Q + qoff + 32 + quad * 8);

  __shared__ u16 VT[80][66];     // rows 0..63: V^T[d][key]; row 64: ones; 65..79: 0
  __shared__ u16 P[4][16][66];   // per-wave P scratch [q][key(64)]

  // static l-channel rows (written once; first in-loop barrier orders vs reads)
  for (int i = tid; i < 16 * 66; i += 256) {
    int r = i / 66;
    VT[64 + r][i - r * 66] = (r == 0) ? (u16)0x3F80 : (u16)0;
  }

  f32x4 zero4 = {0.f, 0.f, 0.f, 0.f};
  f32x4 o[5];                    // o[0..3] = output d-blocks, o[4] col0 = l
  float m_i[4];
#pragma unroll
  for (int dc = 0; dc < 5; dc++) o[dc] = zero4;
#pragma unroll
  for (int r = 0; r < 4; r++) m_i[r] = -INFINITY;

  const int* mrow = mask + (size_t)b * Tk;
  const u16* vptr = Vb + ((size_t)(b * Tk) + lane) * CH + h * HD + wid * 16;
  const u16* kptr = Kb + ((size_t)(b * Tk) + lrow) * CH + h * HD + quad * 8;

  for (int kt = 0; kt < Tk / 64; kt++) {
    int kb = kt * 64;
    // V tile: lane = key, wave = d-block of 16 -> bank = key/2 (conflict-free)
    u16x8 v0 = *reinterpret_cast<const u16x8*>(vptr + (size_t)kb * CH);
    u16x8 v1 = *reinterpret_cast<const u16x8*>(vptr + (size_t)kb * CH + 8);
    __syncthreads();             // prev tile's VT readers done
#pragma unroll
    for (int j = 0; j < 8; j++) VT[wid * 16 + j][lane] = v0[j];
#pragma unroll
    for (int j = 0; j < 8; j++) VT[wid * 16 + 8 + j][lane] = v1[j];
    __syncthreads();

    // S = (scaled Q) K^T  (already in log2 units), masked
    f32x4 s[4];
#pragma unroll
    for (int sub = 0; sub < 4; sub++) {
      const u16* kp = kptr + (size_t)(kb + sub * 16) * CH;
      bf16x8 bk0 = ldbf8(kp);
      bf16x8 bk1 = ldbf8(kp + 32);
      f32x4 z = zero4;
      z = __builtin_amdgcn_mfma_f32_16x16x32_bf16(aq0, bk0, z, 0, 0, 0);
      z = __builtin_amdgcn_mfma_f32_16x16x32_bf16(aq1, bk1, z, 0, 0, 0);
      bool masked = (mrow[kb + sub * 16 + lrow] != 0);
#pragma unroll
      for (int r = 0; r < 4; r++) s[sub][r] = masked ? -INFINITY : z[r];
    }
    // online max (rows = quad*4+r; reduce across 16 col-lanes)
    float rmax[4], alpha[4];
#pragma unroll
    for (int r = 0; r < 4; r++)
      rmax[r] = fmaxf(fmaxf(s[0][r], s[1][r]), fmaxf(s[2][r], s[3][r]));
#pragma unroll
    for (int off = 1; off < 16; off <<= 1)
#pragma unroll
      for (int r = 0; r < 4; r++) rmax[r] = fmaxf(rmax[r], __shfl_xor(rmax[r], off));
#pragma unroll
    for (int r = 0; r < 4; r++) {
      float mnew = fmaxf(m_i[r], rmax[r]);
      alpha[r] = (m_i[r] == -INFINITY) ? 0.f : exp2f(m_i[r] - mnew);
      m_i[r] = mnew;
    }
    // P = exp2(s - m), truncated bf16, into per-wave LDS (C-layout -> A-layout)
#pragma unroll
    for (int sub = 0; sub < 4; sub++)
#pragma unroll
      for (int r = 0; r < 4; r++) {
        float p = (s[sub][r] == -INFINITY) ? 0.f : exp2f(s[sub][r] - m_i[r]);
        P[wid][quad * 4 + r][sub * 16 + lrow] = f2bf_trunc(p);
      }
#pragma unroll
    for (int dc = 0; dc < 5; dc++)
#pragma unroll
      for (int r = 0; r < 4; r++) o[dc][r] *= alpha[r];

    bf16x8 pf0 = ldbf8(&P[wid][lrow][quad * 8]);
    bf16x8 pf1 = ldbf8(&P[wid][lrow][32 + quad * 8]);
#pragma unroll
    for (int dc = 0; dc < 5; dc++) {
      bf16x8 vf0 = ldbf8(&VT[dc * 16 + lrow][quad * 8]);
      bf16x8 vf1 = ldbf8(&VT[dc * 16 + lrow][32 + quad * 8]);
      o[dc] = __builtin_amdgcn_mfma_f32_16x16x32_bf16(pf0, vf0, o[dc], 0, 0, 0);
      o[dc] = __builtin_amdgcn_mfma_f32_16x16x32_bf16(pf1, vf1, o[dc], 0, 0, 0);
    }
  }
  // epilogue: l lives in col lrow==0 of o[4]; broadcast within 16-lane group
#pragma unroll
  for (int r = 0; r < 4; r++) {
    float l = __shfl(o[4][r], lane & 48);
    float linv = 1.0f / l;
    int qr = qt * 64 + wid * 16 + quad * 4 + r;
    size_t yo = ((size_t)(b * Tq + qr)) * CH + h * HD;
#pragma unroll
    for (int dc = 0; dc < 4; dc++)
      Y[yo + dc * 16 + lrow] = f2bf(o[dc][r] * linv);
  }
}

// ------------- final: batch-major xb -> out [T][B][C] fp32 -------------
__global__ void k_out(const float* __restrict__ xb, float* __restrict__ out) {
  size_t i = (size_t)blockIdx.x * 256 + threadIdx.x;
  int c = (int)(i & (CH - 1));
  size_t tb = i >> 10;
  int b = (int)(tb & (BATCH - 1));
  size_t t = tb >> 3;
  out[i] = xb[((size_t)b * T_SEQ + t) * CH + c];
}

extern "C" void kernel_launch(void* const* d_in, const int* in_sizes, int n_in,
                              void* d_out, int out_size, void* d_ws, size_t ws_size,
                              hipStream_t stream) {
  const float* x     = (const float*)d_in[0];
  const float* c     = (const float*)d_in[1];
  const int*   pmask = (const int*)d_in[2];
  const float* audio = (const float*)d_in[3];
  const int*   amask = (const int*)d_in[4];
  const float* w_ada = (const float*)d_in[5];
  const float* b_ada = (const float*)d_in[6];
  const float* wq = (const float*)d_in[7];  const float* bq = (const float*)d_in[8];
  const float* wk = (const float*)d_in[9];  const float* bk = (const float*)d_in[10];
  const float* wv = (const float*)d_in[11]; const float* bv = (const float*)d_in[12];
  const float* wo = (const float*)d_in[13]; const float* bo = (const float*)d_in[14];
  const float* cwq = (const float*)d_in[15]; const float* cbq = (const float*)d_in[16];
  const float* cwk = (const float*)d_in[17]; const float* cbk = (const float*)d_in[18];
  const float* cwv = (const float*)d_in[19]; const float* cbv = (const float*)d_in[20];
  const float* cwo = (const float*)d_in[21]; const float* cbo = (const float*)d_in[22];
  const float* w1 = (const float*)d_in[23]; const float* b1 = (const float*)d_in[24];
  const float* w2 = (const float*)d_in[25]; const float* b2 = (const float*)d_in[26];

  char* wsb = (char*)d_ws;
  size_t off = 0;
  auto alloc = [&](size_t bytes) {
    char* p = wsb + off;
    off += (bytes + 255) & ~(size_t)255;
    return p;
  };
  const size_t SQ = (size_t)CH * CH * 2;       // 2MB bf16 square weight
  u16* wqT  = (u16*)alloc(SQ);
  u16* wkT  = (u16*)alloc(SQ);
  u16* wvT  = (u16*)alloc(SQ);
  u16* woT  = (u16*)alloc(SQ);
  u16* cwqT = (u16*)alloc(SQ);
  u16* cwkT = (u16*)alloc(SQ);
  u16* cwvT = (u16*)alloc(SQ);
  u16* cwoT = (u16*)alloc(SQ);
  u16* w1T  = (u16*)alloc((size_t)CH * MH * 2);
  u16* w2T  = (u16*)alloc((size_t)CH * MH * 2);
  float* mod = (float*)alloc((size_t)BATCH * 6 * CH * 4);
  float* xb  = (float*)alloc((size_t)BATCH * T_SEQ * CH * 4);
  u16* xm    = (u16*)alloc((size_t)BATCH * T_SEQ * CH * 2);
  u16* qbuf  = (u16*)alloc((size_t)BATCH * T_SEQ * CH * 2);   // these four are
  u16* kbuf  = (u16*)alloc((size_t)BATCH * T_SEQ * CH * 2);   // contiguous: hbuf
  u16* vbuf  = (u16*)alloc((size_t)BATCH * T_SEQ * CH * 2);   // (8192x4096 bf16)
  u16* ybuf  = (u16*)alloc((size_t)BATCH * T_SEQ * CH * 2);   // aliases them
  u16* hbuf  = qbuf;
  u16* abuf  = (u16*)alloc((size_t)BATCH * TA_SEQ * CH * 2);
  (void)ws_size; (void)in_sizes; (void)n_in; (void)out_size;

  const int NE = T_SEQ * BATCH * CH;   // 8.39M elements
  dim3 tb32(32, 8);

  // weights -> bf16 transposed
  k_transpose_w<<<dim3(CH / 32, CH / 32), tb32, 0, stream>>>(wq, wqT, CH, CH);
  k_transpose_w<<<dim3(CH / 32, CH / 32), tb32, 0, stream>>>(wk, wkT, CH, CH);
  k_transpose_w<<<dim3(CH / 32, CH / 32), tb32, 0, stream>>>(wv, wvT, CH, CH);
  k_transpose_w<<<dim3(CH / 32, CH / 32), tb32, 0, stream>>>(wo, woT, CH, CH);
  k_transpose_w<<<dim3(CH / 32, CH / 32), tb32, 0, stream>>>(cwq, cwqT, CH, CH);
  k_transpose_w<<<dim3(CH / 32, CH / 32), tb32, 0, stream>>>(cwk, cwkT, CH, CH);
  k_transpose_w<<<dim3(CH / 32, CH / 32), tb32, 0, stream>>>(cwv, cwvT, CH, CH);
  k_transpose_w<<<dim3(CH / 32, CH / 32), tb32, 0, stream>>>(cwo, cwoT, CH, CH);
  k_transpose_w<<<dim3(MH / 32, CH / 32), tb32, 0, stream>>>(w1, w1T, CH, MH);
  k_transpose_w<<<dim3(CH / 32, MH / 32), tb32, 0, stream>>>(w2, w2T, MH, CH);

  k_ada<<<dim3(6 * CH / 256, BATCH), 256, 0, stream>>>(c, w_ada, b_ada, mod);
  k_tbc_to_btc_f32<<<NE / 256, 256, 0, stream>>>(x, xb);
  k_tbc_to_btc_bf16<<<NE / 256, 256, 0, stream>>>(audio, abuf);

  // ---- self-attention ----
  k_ln_mod<<<BATCH * T_SEQ, 256, 0, stream>>>(xb, mod, xm, 0, 1);
  k_gemm<3><<<dim3(64, 8), 256, 0, stream>>>(xm, wqT, bq, qbuf, nullptr, nullptr, 0, 8192, CH, CH);
  k_gemm<0><<<dim3(64, 8), 256, 0, stream>>>(xm, wkT, bk, kbuf, nullptr, nullptr, 0, 8192, CH, CH);
  k_gemm<0><<<dim3(64, 8), 256, 0, stream>>>(xm, wvT, bv, vbuf, nullptr, nullptr, 0, 8192, CH, CH);
  k_attn<<<dim3(T_SEQ / 64, NH, BATCH), 256, 0, stream>>>(qbuf, kbuf, vbuf, pmask, ybuf, T_SEQ, T_SEQ);
  k_gemm<1><<<dim3(64, 8), 256, 0, stream>>>(ybuf, woT, bo, nullptr, xb, mod, 2, 8192, CH, CH);

  // ---- cross-attention (reuses msa shift/scale/gate) ----
  k_ln_mod<<<BATCH * T_SEQ, 256, 0, stream>>>(xb, mod, xm, 0, 1);
  k_gemm<3><<<dim3(64, 8), 256, 0, stream>>>(xm, cwqT, cbq, qbuf, nullptr, nullptr, 0, 8192, CH, CH);
  k_gemm<0><<<dim3(64, 8), 256, 0, stream>>>(abuf, cwkT, cbk, kbuf, nullptr, nullptr, 0, 8192, CH, CH);
  k_gemm<0><<<dim3(64, 8), 256, 0, stream>>>(abuf, cwvT, cbv, vbuf, nullptr, nullptr, 0, 8192, CH, CH);
  k_attn<<<dim3(T_SEQ / 64, NH, BATCH), 256, 0, stream>>>(qbuf, kbuf, vbuf, amask, ybuf, T_SEQ, TA_SEQ);
  k_gemm<1><<<dim3(64, 8), 256, 0, stream>>>(ybuf, cwoT, cbo, nullptr, xb, mod, 2, 8192, CH, CH);

  // ---- MLP ----
  k_ln_mod<<<BATCH * T_SEQ, 256, 0, stream>>>(xb, mod, xm, 3, 4);
  k_gemm<2><<<dim3(64, 32), 256, 0, stream>>>(xm, w1T, b1, hbuf, nullptr, nullptr, 0, 8192, MH, CH);
  k_gemm<1><<<dim3(64, 8), 256, 0, stream>>>(hbuf, w2T, b2, nullptr, xb, mod, 5, 8192, CH, MH);

  k_out<<<NE / 256, 256, 0, stream>>>(xb, (float*)d_out);
}